// Round 1
// baseline (79.338 us; speedup 1.0000x reference)
//
#include <hip/hip_runtime.h>
#include <math.h>

#define HH 8
#define DD 32
#define LL 512
#define LN_EPS 1e-5f
// 1/(3*sqrt(32))
#define KSCALE 0.058925565098878960f

// ---------------- Kernel 1: LayerNorm rows (Q and K) ----------------
// rows 0..4095 = queries (l*H+h), rows 4096..8191 = keys (s*H+h)
__global__ __launch_bounds__(256) void ln_kernel(
    const float* __restrict__ q_in, const float* __restrict__ k_in,
    const float* __restrict__ key_len,
    float* __restrict__ Qn, float* __restrict__ Kn)
{
    int t = threadIdx.x;
    int lane = t & 31;
    int row = blockIdx.x * 8 + (t >> 5);      // 0..8191
    bool isK = row >= 4096;
    int r = isK ? row - 4096 : row;           // 0..4095
    const float* src = isK ? k_in : q_in;
    float x = src[r * 32 + lane];
    float m = x;
    #pragma unroll
    for (int off = 16; off > 0; off >>= 1) m += __shfl_xor(m, off, 32);
    m *= (1.0f / 32.0f);
    float c = x - m;
    float v = c * c;
    #pragma unroll
    for (int off = 16; off > 0; off >>= 1) v += __shfl_xor(v, off, 32);
    v *= (1.0f / 32.0f);
    float y = c * rsqrtf(v + LN_EPS);
    if (isK) {
        int s = r >> 3;                        // r = s*H + h
        y *= KSCALE * key_len[s];
        Kn[r * 32 + lane] = y;
    } else {
        Qn[r * 32 + lane] = y;
    }
}

// ---------------- Kernel 2: per-head reductions ----------------
// grid = 64: h = bid>>3, s-chunk = bid&7 (64 rows each).
// Produces KV[h][m][d], KK[h][d][e], QQ[h][d][e], Ksum[h][d] via atomicAdd.
__global__ __launch_bounds__(256) void head_reduce_kernel(
    const float* __restrict__ Qn, const float* __restrict__ Kn,
    const float* __restrict__ v_in,
    float* __restrict__ KV, float* __restrict__ KK,
    float* __restrict__ QQ, float* __restrict__ Ksum)
{
    __shared__ float Ks[64 * 32];
    __shared__ float Vs[64 * 32];
    __shared__ float Qs[64 * 32];
    int h = blockIdx.x >> 3;
    int s0 = (blockIdx.x & 7) * 64;
    int t = threadIdx.x;
    for (int i = t; i < 64 * 32; i += 256) {
        int s = i >> 5, d = i & 31;
        int g = ((s0 + s) * HH + h) * 32 + d;
        Ks[i] = Kn[g];
        Vs[i] = v_in[g];
        Qs[i] = Qn[g];
    }
    __syncthreads();
    int grp = t >> 5;       // 0..7  -> d = grp + j*8
    int lane = t & 31;      // e / m index
    float kv[4] = {0, 0, 0, 0};
    float kk[4] = {0, 0, 0, 0};
    float qq[4] = {0, 0, 0, 0};
    #pragma unroll 4
    for (int s = 0; s < 64; ++s) {
        float ke = Ks[s * 32 + lane];
        float ve = Vs[s * 32 + lane];
        float qe = Qs[s * 32 + lane];
        #pragma unroll
        for (int j = 0; j < 4; ++j) {
            int d = grp + j * 8;
            float kd = Ks[s * 32 + d];   // broadcast within 32-lane group
            float qd = Qs[s * 32 + d];
            kv[j] += kd * ve;
            kk[j] += kd * ke;
            qq[j] += qd * qe;
        }
    }
    #pragma unroll
    for (int j = 0; j < 4; ++j) {
        int d = grp + j * 8;
        atomicAdd(&KV[h * 1024 + lane * 32 + d], kv[j]);  // KV[h][m][d]
        atomicAdd(&KK[h * 1024 + d * 32 + lane], kk[j]);  // KK[h][d][e]
        atomicAdd(&QQ[h * 1024 + d * 32 + lane], qq[j]);  // QQ[h][d][e]
    }
    if (t < 32) {
        float acc = 0.0f;
        for (int s = 0; s < 64; ++s) acc += Ks[s * 32 + t];
        atomicAdd(&Ksum[h * 32 + t], acc);
    }
}

// ---------------- Kernel 3: finalize ----------------
// grid = 512: h = bid>>6, 8 l-rows per block (one 32-lane group per row).
__global__ __launch_bounds__(256) void finalize_kernel(
    const float* __restrict__ Qn, const float* __restrict__ Kn,
    const float* __restrict__ v_in,
    const float* __restrict__ KV, const float* __restrict__ KK,
    const float* __restrict__ QQ, const float* __restrict__ Ksum,
    float* __restrict__ out)
{
    // stride 33 padding: row-wise reads KKs[lane*33+e] hit bank (lane+e)%32 -> conflict-free
    __shared__ float KVs[32 * 33];
    __shared__ float KKs[32 * 33];
    __shared__ float QQs[32 * 33];
    __shared__ float Ks_s[32];
    __shared__ float qsh[8][32];
    __shared__ float ksh[8][32];
    int h = blockIdx.x >> 6;
    int lb = blockIdx.x & 63;
    int t = threadIdx.x;
    int lane = t & 31;      // d (for norm terms) and m (for output)
    int rl = t >> 5;        // local row 0..7
    int l = lb * 8 + rl;

    for (int i = t; i < 1024; i += 256) {
        int r = i >> 5, c = i & 31;
        KVs[r * 33 + c] = KV[h * 1024 + i];
        KKs[r * 33 + c] = KK[h * 1024 + i];
        QQs[r * 33 + c] = QQ[h * 1024 + i];
    }
    if (t < 32) Ks_s[t] = Ksum[h * 32 + t];

    int gidx = (l * HH + h) * 32 + lane;
    float qd = Qn[gidx];
    float kd = Kn[gidx];
    float vm = v_in[gidx];
    qsh[rl][lane] = qd;
    ksh[rl][lane] = kd;
    __syncthreads();

    float s1 = 0.0f;   // (KK q)[d]
    float s2 = 0.0f;   // (QQ k)[d]
    float o1 = 0.0f;   // order1[m] = KV[m,:]·q
    #pragma unroll 8
    for (int e = 0; e < 32; ++e) {
        float qe = qsh[rl][e];
        s1 += KKs[lane * 33 + e] * qe;
        s2 += QQs[lane * 33 + e] * ksh[rl][e];
        o1 += KVs[lane * 33 + e] * qe;
    }
    float normp = qd * Ks_s[lane] + 0.5f * qd * s1;
    float kq2p = kd * s2;
    #pragma unroll
    for (int off = 16; off > 0; off >>= 1) {
        normp += __shfl_xor(normp, off, 32);
        kq2p  += __shfl_xor(kq2p, off, 32);
    }
    out[gidx] = (o1 + 0.5f * kq2p * vm) / normp;
}

extern "C" void kernel_launch(void* const* d_in, const int* in_sizes, int n_in,
                              void* d_out, int out_size, void* d_ws, size_t ws_size,
                              hipStream_t stream) {
    const float* q_in   = (const float*)d_in[0];
    const float* k_in   = (const float*)d_in[1];
    const float* v_in   = (const float*)d_in[2];
    // d_in[3] attn_mask (all ones, unused by reference), d_in[4] query_lengths (unused)
    const float* key_len = (const float*)d_in[5];

    float* ws   = (float*)d_ws;
    float* Qn   = ws;                  // 131072
    float* Kn   = ws + 131072;         // 131072
    float* KV   = ws + 262144;         // 8*1024
    float* KK   = KV + 8192;
    float* QQ   = KK + 8192;
    float* Ksum = QQ + 8192;           // 8*32
    float* out  = (float*)d_out;

    hipMemsetAsync(KV, 0, (3 * 8192 + 256) * sizeof(float), stream);
    ln_kernel<<<1024, 256, 0, stream>>>(q_in, k_in, key_len, Qn, Kn);
    head_reduce_kernel<<<64, 256, 0, stream>>>(Qn, Kn, v_in, KV, KK, QQ, Ksum);
    finalize_kernel<<<512, 256, 0, stream>>>(Qn, Kn, v_in, KV, KK, QQ, Ksum, out);
}